// Round 3
// baseline (708.982 us; speedup 1.0000x reference)
//
#include <hip/hip_runtime.h>
#include <hip/hip_bf16.h>

#define CIN 64
#define COUT 32

// ======================= Inverted (CSR) pipeline =======================

// Phase A: per-k GEMV -> contrib[k*P+p][COUT] in bf16 (no atomics).
__global__ __launch_bounds__(256) void contrib_kernel(
    const float* __restrict__ feats,
    const float* __restrict__ weight,
    const int* __restrict__ in_idx,
    __hip_bfloat16* __restrict__ contrib,
    int P, int n_groups)
{
    const int k        = blockIdx.y;
    const int lane     = threadIdx.x & 31;
    const int group_id = blockIdx.x * (blockDim.x >> 5) + (threadIdx.x >> 5);

    float w[CIN];
    const float* __restrict__ Wk = weight + (long)k * CIN * COUT;
    #pragma unroll
    for (int c = 0; c < CIN; ++c) w[c] = Wk[c * COUT + lane];

    const int base    = k * P;
    const int nchunks = (P + 31) >> 5;

    for (int ch = group_id; ch < nchunks; ch += n_groups) {
        const int p0 = ch << 5;
        const int n  = min(32, P - p0);

        int my_in = 0;
        if (lane < n) my_in = in_idx[base + p0 + lane];

        #pragma unroll 4
        for (int j = 0; j < n; ++j) {
            const int in = __shfl(my_in, j, 32);
            const float4* __restrict__ fr =
                reinterpret_cast<const float4*>(feats + (long)in * CIN);
            float acc = 0.0f;
            #pragma unroll
            for (int c4 = 0; c4 < CIN / 4; ++c4) {
                float4 f = fr[c4];
                acc += f.x * w[4 * c4 + 0];
                acc += f.y * w[4 * c4 + 1];
                acc += f.z * w[4 * c4 + 2];
                acc += f.w * w[4 * c4 + 3];
            }
            contrib[(long)(base + p0 + j) * COUT + lane] = __float2bfloat16(acc);
        }
    }
}

// Phase B0: zero the histogram.
__global__ __launch_bounds__(256) void zero_kernel(int* __restrict__ rb, int n)
{
    int i = blockIdx.x * blockDim.x + threadIdx.x;
    if (i < n) rb[i] = 0;
}

// Phase B1: histogram of out_idx.
__global__ __launch_bounds__(256) void hist_kernel(
    const int* __restrict__ out_idx, int* __restrict__ rb, int total)
{
    int i = blockIdx.x * blockDim.x + threadIdx.x;
    if (i < total) atomicAdd(&rb[out_idx[i]], 1);
}

// Phase B2a: per-block exclusive scan (256 elems) + block sums.
__global__ __launch_bounds__(256) void scan_blocks_kernel(
    int* __restrict__ rb, int* __restrict__ bsums, int n)
{
    __shared__ int s[256];
    int i = blockIdx.x * 256 + threadIdx.x;
    int v = (i < n) ? rb[i] : 0;
    s[threadIdx.x] = v;
    __syncthreads();
    #pragma unroll
    for (int d = 1; d < 256; d <<= 1) {
        int t = (threadIdx.x >= d) ? s[threadIdx.x - d] : 0;
        __syncthreads();
        s[threadIdx.x] += t;
        __syncthreads();
    }
    if (i < n) rb[i] = s[threadIdx.x] - v;          // exclusive within block
    if (threadIdx.x == 255) bsums[blockIdx.x] = s[255];
}

// Phase B2b: exclusive scan of block sums (single block).
#define MAXM 8
__global__ __launch_bounds__(256) void scan_bsums_kernel(int* __restrict__ bsums, int nb)
{
    __shared__ int s[256];
    const int t = threadIdx.x;
    const int base = t * MAXM;
    int loc[MAXM];
    int sum = 0;
    #pragma unroll
    for (int m = 0; m < MAXM; ++m) {
        int idx = base + m;
        int v = (idx < nb) ? bsums[idx] : 0;
        loc[m] = sum;                // exclusive within chunk
        sum += v;
    }
    s[t] = sum;
    __syncthreads();
    #pragma unroll
    for (int d = 1; d < 256; d <<= 1) {
        int tv = (t >= d) ? s[t - d] : 0;
        __syncthreads();
        s[t] += tv;
        __syncthreads();
    }
    int off = s[t] - sum;            // exclusive across chunks
    #pragma unroll
    for (int m = 0; m < MAXM; ++m) {
        int idx = base + m;
        if (idx < nb) bsums[idx] = off + loc[m];
    }
}

// Phase B2c: add scanned block sums -> rb = global row starts.
__global__ __launch_bounds__(256) void add_offsets_kernel(
    int* __restrict__ rb, const int* __restrict__ bsums, int n)
{
    int i = blockIdx.x * blockDim.x + threadIdx.x;
    if (i < n) rb[i] += bsums[i >> 8];
}

// Phase B3: fill records. After this, rb[o] = end(o) (= start(o+1)).
__global__ __launch_bounds__(256) void fill_kernel(
    const int* __restrict__ out_idx, int* __restrict__ rb,
    int* __restrict__ records, int total)
{
    int i = blockIdx.x * blockDim.x + threadIdx.x;
    if (i < total) {
        int o = out_idx[i];
        int pos = atomicAdd(&rb[o], 1);
        records[pos] = i;
    }
}

// Phase C: one 32-lane group per output row; gather contribs, add bias, store.
__global__ __launch_bounds__(256) void reduce_kernel(
    const __hip_bfloat16* __restrict__ contrib,
    const int* __restrict__ records,
    const int* __restrict__ rb,      // rb[o] = end(o) after fill
    const float* __restrict__ bias,
    float* __restrict__ out, int n_out)
{
    int gid  = blockIdx.x * (blockDim.x >> 5) + (threadIdx.x >> 5);
    int lane = threadIdx.x & 31;
    if (gid >= n_out) return;
    int end   = rb[gid];
    int start = (gid == 0) ? 0 : rb[gid - 1];
    float acc = bias[lane];
    for (int e = start; e < end; ++e) {
        int rec = records[e];
        acc += __bfloat162float(contrib[(long)rec * COUT + lane]);
    }
    out[(long)gid * COUT + lane] = acc;
}

// ======================= Fallback (R2 atomic path) =======================

__global__ __launch_bounds__(256) void bias_init_kernel(
    float* __restrict__ out, const float* __restrict__ bias, int total)
{
    int i = (blockIdx.x * blockDim.x + threadIdx.x) * 4;
    if (i < total) {
        int ch = i & (COUT - 1);
        float4 b;
        b.x = bias[ch + 0]; b.y = bias[ch + 1];
        b.z = bias[ch + 2]; b.w = bias[ch + 3];
        *reinterpret_cast<float4*>(out + i) = b;
    }
}

__global__ __launch_bounds__(256) void scatter_gemm_kernel(
    const float* __restrict__ feats,
    const float* __restrict__ weight,
    const int* __restrict__ in_idx,
    const int* __restrict__ out_idx,
    float* __restrict__ out,
    int P, int n_groups)
{
    const int k        = blockIdx.y;
    const int lane     = threadIdx.x & 31;
    const int group_id = blockIdx.x * (blockDim.x >> 5) + (threadIdx.x >> 5);

    float w[CIN];
    const float* __restrict__ Wk = weight + (long)k * CIN * COUT;
    #pragma unroll
    for (int c = 0; c < CIN; ++c) w[c] = Wk[c * COUT + lane];

    const int base    = k * P;
    const int nchunks = (P + 31) >> 5;
    for (int ch = group_id; ch < nchunks; ch += n_groups) {
        const int p0 = ch << 5;
        const int n  = min(32, P - p0);
        int my_in = 0, my_out = 0;
        if (lane < n) {
            my_in  = in_idx[base + p0 + lane];
            my_out = out_idx[base + p0 + lane];
        }
        #pragma unroll 4
        for (int j = 0; j < n; ++j) {
            const int in = __shfl(my_in,  j, 32);
            const int o  = __shfl(my_out, j, 32);
            const float4* __restrict__ fr =
                reinterpret_cast<const float4*>(feats + (long)in * CIN);
            float acc = 0.0f;
            #pragma unroll
            for (int c4 = 0; c4 < CIN / 4; ++c4) {
                float4 f = fr[c4];
                acc += f.x * w[4 * c4 + 0];
                acc += f.y * w[4 * c4 + 1];
                acc += f.z * w[4 * c4 + 2];
                acc += f.w * w[4 * c4 + 3];
            }
            atomicAdd(out + (long)o * COUT + lane, acc);
        }
    }
}

// ======================= launch =======================

extern "C" void kernel_launch(void* const* d_in, const int* in_sizes, int n_in,
                              void* d_out, int out_size, void* d_ws, size_t ws_size,
                              hipStream_t stream) {
    const float* feats   = (const float*)d_in[0];
    const float* weight  = (const float*)d_in[1];
    const float* bias    = (const float*)d_in[2];
    const int*   in_idx  = (const int*)d_in[3];
    const int*   out_idx = (const int*)d_in[4];
    float*       out     = (float*)d_out;

    const int K     = in_sizes[1] / (CIN * COUT);   // 27
    const int P     = in_sizes[3] / K;              // 50000
    const int total = K * P;                        // 1.35M
    const int n_out = out_size / COUT;              // 400000
    const int nblk  = (n_out + 255) / 256;          // scan blocks (1563)

    // Workspace layout (256B aligned).
    size_t off = 0;
    auto take = [&](size_t bytes) {
        size_t o = off;
        off = (off + bytes + 255) & ~(size_t)255;
        return o;
    };
    size_t rb_off      = take((size_t)n_out * 4);
    size_t bsums_off   = take((size_t)nblk * 4);
    size_t records_off = take((size_t)total * 4);
    size_t contrib_off = take((size_t)total * COUT * 2);

    if (off > ws_size || nblk > 256 * MAXM) {
        // Fallback: direct atomic scatter (R2 path).
        int total4 = out_size / 4;
        bias_init_kernel<<<(total4 + 255) / 256, 256, 0, stream>>>(out, bias, out_size);
        const int blocks_x = 96;
        const int n_groups = blocks_x * (256 / 32);
        dim3 grid(blocks_x, K);
        scatter_gemm_kernel<<<grid, 256, 0, stream>>>(feats, weight, in_idx, out_idx,
                                                      out, P, n_groups);
        return;
    }

    char* ws = (char*)d_ws;
    int*            rb      = (int*)(ws + rb_off);
    int*            bsums   = (int*)(ws + bsums_off);
    int*            records = (int*)(ws + records_off);
    __hip_bfloat16* contrib = (__hip_bfloat16*)(ws + contrib_off);

    // Phase A: contributions (independent of B; stream serializes anyway).
    {
        const int blocks_x = 96;
        const int n_groups = blocks_x * (256 / 32);
        dim3 grid(blocks_x, K);
        contrib_kernel<<<grid, 256, 0, stream>>>(feats, weight, in_idx, contrib,
                                                 P, n_groups);
    }

    // Phase B: CSR inversion of out_idx.
    zero_kernel<<<(n_out + 255) / 256, 256, 0, stream>>>(rb, n_out);
    hist_kernel<<<(total + 255) / 256, 256, 0, stream>>>(out_idx, rb, total);
    scan_blocks_kernel<<<nblk, 256, 0, stream>>>(rb, bsums, n_out);
    scan_bsums_kernel<<<1, 256, 0, stream>>>(bsums, nblk);
    add_offsets_kernel<<<(n_out + 255) / 256, 256, 0, stream>>>(rb, bsums, n_out);
    fill_kernel<<<(total + 255) / 256, 256, 0, stream>>>(out_idx, rb, records, total);

    // Phase C: per-row gather-reduce, single store per row.
    reduce_kernel<<<(n_out * 32 + 255) / 256, 256, 0, stream>>>(
        contrib, records, rb, bias, out, n_out);
}

// Round 4
// 166.159 us; speedup vs baseline: 4.2669x; 4.2669x over previous
//
#include <hip/hip_runtime.h>

#define CIN 64
#define COUT 32

typedef __attribute__((ext_vector_type(8))) short bf16x8;
typedef __attribute__((ext_vector_type(4))) float f32x4;

__device__ inline ushort f2bf(float x) {
    union { float f; unsigned u; } v; v.f = x;
    unsigned r = v.u + 0x7fff + ((v.u >> 16) & 1);   // RNE
    return (ushort)(r >> 16);
}

// fp32 -> bf16 conversion, 4 elems/thread.
__global__ __launch_bounds__(256) void cvt_kernel(
    const float* __restrict__ in, ushort* __restrict__ outb, int n4)
{
    int i = blockIdx.x * blockDim.x + threadIdx.x;
    if (i < n4) {
        float4 f = reinterpret_cast<const float4*>(in)[i];
        ushort4 u;
        u.x = f2bf(f.x); u.y = f2bf(f.y); u.z = f2bf(f.z); u.w = f2bf(f.w);
        reinterpret_cast<ushort4*>(outb)[i] = u;
    }
}

// out[r, c] = bias[c] for all rows.
__global__ __launch_bounds__(256) void bias_init_kernel(
    float* __restrict__ out, const float* __restrict__ bias, int total)
{
    int i = (blockIdx.x * blockDim.x + threadIdx.x) * 4;
    if (i < total) {
        int ch = i & (COUT - 1);
        float4 b;
        b.x = bias[ch + 0]; b.y = bias[ch + 1];
        b.z = bias[ch + 2]; b.w = bias[ch + 3];
        *reinterpret_cast<float4*>(out + i) = b;
    }
}

// One wave per 16-pair tile (grid-stride): per-lane-parallel gather of 16
// random feats rows, 4 MFMAs (2 K-steps x 2 N-tiles), atomic scatter.
// MFMA 16x16x32 layouts: A: row=lane&15, k=8*(lane>>4)+e;
//                        B: col=lane&15, k=8*(lane>>4)+e;
//                        C: col=lane&15, row=4*(lane>>4)+r.
__global__ __launch_bounds__(256) void mfma_scatter_kernel(
    const ushort* __restrict__ featsb,   // [N_IN][64] bf16
    const ushort* __restrict__ wb,       // [K][64][32] bf16
    const int* __restrict__ in_idx,
    const int* __restrict__ out_idx,
    float* __restrict__ out,
    int P, int ntiles, int waves_per_k)
{
    const int k    = blockIdx.y;
    const int lane = threadIdx.x & 63;
    const int wav  = blockIdx.x * (blockDim.x >> 6) + (threadIdx.x >> 6);

    const int col = lane & 15;
    const int kch = lane >> 4;           // 0..3: which 8-wide k-chunk

    // B fragments, block-uniform per k: bfrag[kstep][ntile].
    bf16x8 bfrag[2][2];
    {
        const ushort* __restrict__ W = wb + k * CIN * COUT;
        #pragma unroll
        for (int ks = 0; ks < 2; ++ks)
            #pragma unroll
            for (int nt = 0; nt < 2; ++nt) {
                bf16x8 t;
                #pragma unroll
                for (int e = 0; e < 8; ++e)
                    t[e] = (short)W[(ks * 32 + kch * 8 + e) * COUT + nt * 16 + col];
                bfrag[ks][nt] = t;
            }
    }

    const int base = k * P;
    for (int tile = wav; tile < ntiles; tile += waves_per_k) {
        const int p0 = tile << 4;

        // Gather A: lane's M-row = pair p0+col; 2 x 16B loads per lane.
        const int pA  = min(p0 + col, P - 1);
        const int row = in_idx[base + pA];
        const ushort* __restrict__ ar = featsb + (long)row * CIN + kch * 8;
        bf16x8 a0 = *reinterpret_cast<const bf16x8*>(ar);
        bf16x8 a1 = *reinterpret_cast<const bf16x8*>(ar + 32);

        f32x4 acc0 = {0.f, 0.f, 0.f, 0.f};
        f32x4 acc1 = {0.f, 0.f, 0.f, 0.f};
        acc0 = __builtin_amdgcn_mfma_f32_16x16x32_bf16(a0, bfrag[0][0], acc0, 0, 0, 0);
        acc0 = __builtin_amdgcn_mfma_f32_16x16x32_bf16(a1, bfrag[1][0], acc0, 0, 0, 0);
        acc1 = __builtin_amdgcn_mfma_f32_16x16x32_bf16(a0, bfrag[0][1], acc1, 0, 0, 0);
        acc1 = __builtin_amdgcn_mfma_f32_16x16x32_bf16(a1, bfrag[1][1], acc1, 0, 0, 0);

        // Scatter: lane handles rows 4*kch..4*kch+3, cols {col, col+16}.
        #pragma unroll
        for (int r = 0; r < 4; ++r) {
            const int prow = p0 + kch * 4 + r;
            if (prow < P) {
                const int orow = out_idx[base + prow];
                float* dst = out + (long)orow * COUT + col;
                atomicAdd(dst,      acc0[r]);
                atomicAdd(dst + 16, acc1[r]);
            }
        }
    }
}

// ======================= Fallback (R2 atomic path) =======================

__global__ __launch_bounds__(256) void scatter_gemm_kernel(
    const float* __restrict__ feats,
    const float* __restrict__ weight,
    const int* __restrict__ in_idx,
    const int* __restrict__ out_idx,
    float* __restrict__ out,
    int P, int n_groups)
{
    const int k        = blockIdx.y;
    const int lane     = threadIdx.x & 31;
    const int group_id = blockIdx.x * (blockDim.x >> 5) + (threadIdx.x >> 5);

    float w[CIN];
    const float* __restrict__ Wk = weight + (long)k * CIN * COUT;
    #pragma unroll
    for (int c = 0; c < CIN; ++c) w[c] = Wk[c * COUT + lane];

    const int base    = k * P;
    const int nchunks = (P + 31) >> 5;
    for (int ch = group_id; ch < nchunks; ch += n_groups) {
        const int p0 = ch << 5;
        const int n  = min(32, P - p0);
        int my_in = 0, my_out = 0;
        if (lane < n) {
            my_in  = in_idx[base + p0 + lane];
            my_out = out_idx[base + p0 + lane];
        }
        #pragma unroll 4
        for (int j = 0; j < n; ++j) {
            const int in = __shfl(my_in,  j, 32);
            const int o  = __shfl(my_out, j, 32);
            const float4* __restrict__ fr =
                reinterpret_cast<const float4*>(feats + (long)in * CIN);
            float acc = 0.0f;
            #pragma unroll
            for (int c4 = 0; c4 < CIN / 4; ++c4) {
                float4 f = fr[c4];
                acc += f.x * w[4 * c4 + 0];
                acc += f.y * w[4 * c4 + 1];
                acc += f.z * w[4 * c4 + 2];
                acc += f.w * w[4 * c4 + 3];
            }
            atomicAdd(out + (long)o * COUT + lane, acc);
        }
    }
}

// ======================= launch =======================

extern "C" void kernel_launch(void* const* d_in, const int* in_sizes, int n_in,
                              void* d_out, int out_size, void* d_ws, size_t ws_size,
                              hipStream_t stream) {
    const float* feats   = (const float*)d_in[0];
    const float* weight  = (const float*)d_in[1];
    const float* bias    = (const float*)d_in[2];
    const int*   in_idx  = (const int*)d_in[3];
    const int*   out_idx = (const int*)d_in[4];
    float*       out     = (float*)d_out;

    const int K     = in_sizes[1] / (CIN * COUT);   // 27
    const int P     = in_sizes[3] / K;              // 50000
    const int n_feat = in_sizes[0];                 // N_IN*CIN
    const int n_w    = in_sizes[1];                 // K*CIN*COUT

    // Workspace: bf16 feats + bf16 weights.
    size_t featsb_bytes = (size_t)n_feat * 2;
    size_t wb_off       = (featsb_bytes + 255) & ~(size_t)255;
    size_t need         = wb_off + (size_t)n_w * 2;

    // out = bias broadcast (atomics accumulate on top).
    int total4 = out_size / 4;
    bias_init_kernel<<<(total4 + 255) / 256, 256, 0, stream>>>(out, bias, out_size);

    if (need > ws_size) {
        // Fallback: R2 vector path.
        const int blocks_x = 96;
        const int n_groups = blocks_x * (256 / 32);
        dim3 grid(blocks_x, K);
        scatter_gemm_kernel<<<grid, 256, 0, stream>>>(feats, weight, in_idx, out_idx,
                                                      out, P, n_groups);
        return;
    }

    ushort* featsb = (ushort*)d_ws;
    ushort* wb     = (ushort*)((char*)d_ws + wb_off);

    cvt_kernel<<<(n_feat / 4 + 255) / 256, 256, 0, stream>>>(feats, featsb, n_feat / 4);
    cvt_kernel<<<(n_w / 4 + 255) / 256, 256, 0, stream>>>(weight, wb, n_w / 4);

    const int ntiles   = (P + 15) / 16;             // 3125
    const int blocks_x = 196;                       // 784 waves/k -> ~4 tiles/wave
    const int waves_per_k = blocks_x * (256 / 64);
    dim3 grid(blocks_x, K);
    mfma_scatter_kernel<<<grid, 256, 0, stream>>>(featsb, wb, in_idx, out_idx, out,
                                                  P, ntiles, waves_per_k);
}